// Round 2
// baseline (146.881 us; speedup 1.0000x reference)
//
#include <hip/hip_runtime.h>
#include <hip/hip_bf16.h>

// AttentionDot: B=16, TQ=128, TK=8192, H=256, fp32 in/out.
// Flash split-K attention, f16 MFMA 32x32x16, fp32 accumulate.
// Main: 512 blocks (b x 32 ksplits) x 256 thr (4 waves, each 32q x 256h),
//       2 blocks/CU. Combine merges 32 splits.
// ws: 32 MiB packed-f16 partial ctx + 512 KiB fp32 (m,l).

typedef _Float16 half8 __attribute__((ext_vector_type(8)));
typedef float floatx16 __attribute__((ext_vector_type(16)));
typedef unsigned int u32;

#define NB 16
#define TQ 128
#define TK 8192
#define HD 256
#define KSPLIT 32
#define KEYS_PER_SPLIT (TK / KSPLIT) /* 256 */
#define KB 32
#define NSUB (KEYS_PER_SPLIT / KB)   /* 8 */

// LDS (64 KiB/block):
//   K bufs: 2 x [32 k][256 h] f16, row 512B, byte-in-row = (2h)^((k&7)<<4)   @ 0, 16384
//   V bufs: 2 x [4 vrow=kk>>3][256 slot][8 kk&7] f16, slot = h^((h>>3)&7)^vrow @ 32768, 49152

__global__ __launch_bounds__(256, 2) void attn_main(
    const float* __restrict__ enc, const float* __restrict__ dec,
    u32* __restrict__ pctx, float* __restrict__ pml) {
  __shared__ __align__(16) unsigned char smem[65536];
  const int tid = threadIdx.x;
  const int lane = tid & 63, wave = tid >> 6;  // wave = q-tile index 0..3
  const int l31 = lane & 31, g2 = lane >> 5;
  const int b = blockIdx.x >> 5, ks = blockIdx.x & 31;

  // ---- Q fragments in registers: qf[c] holds Q[q=l31][c*16 + g2*8 + j] ----
  half8 qf[16];
  {
    const float* qrow = dec + (size_t)(b * TQ + wave * 32 + l31) * HD;
#pragma unroll
    for (int c = 0; c < 16; ++c) {
      const float4* p4 = (const float4*)(qrow + c * 16 + g2 * 8);
      float4 x = p4[0], y = p4[1];
      half8 v;
      v[0] = (_Float16)x.x; v[1] = (_Float16)x.y; v[2] = (_Float16)x.z; v[3] = (_Float16)x.w;
      v[4] = (_Float16)y.x; v[5] = (_Float16)y.y; v[6] = (_Float16)y.z; v[7] = (_Float16)y.w;
      qf[c] = v;
    }
  }

  floatx16 ctx[8];
#pragma unroll
  for (int t = 0; t < 8; ++t)
#pragma unroll
    for (int i = 0; i < 16; ++i) ctx[t][i] = 0.f;
  float mrun = -1e30f, lrun = 0.f;

  const size_t keybase = (size_t)b * TK + (size_t)ks * KEYS_PER_SPLIT;
  const int sh0 = (tid & 63) * 4;   // 4 h columns per thread
  const int sr0 = (tid >> 6) * 8;   // 8 key rows per thread
  const int vrw = tid >> 6;         // V row block (kk>>3)

  float la[4][4], lb[4][4];  // two half-stages (rows sr0+0..3, sr0+4..7)

  auto LOADH = [&](int sc, int half, float (&lv)[4][4]) {
#pragma unroll
    for (int j = 0; j < 4; ++j) {
      float4 t = *(const float4*)(
          enc + (keybase + (size_t)sc * KB + sr0 + half * 4 + j) * HD + sh0);
      lv[j][0] = t.x; lv[j][1] = t.y; lv[j][2] = t.z; lv[j][3] = t.w;
    }
  };

  auto WRITEH = [&](int buf, int half, float (&lv)[4][4]) {
    unsigned char* kb_ = smem + buf * 16384;
    unsigned char* vb_ = smem + 32768 + buf * 16384;
#pragma unroll
    for (int j = 0; j < 4; ++j) {
      int r = sr0 + half * 4 + j;
      u32 w0 = __builtin_bit_cast(u32, __builtin_amdgcn_cvt_pkrtz(lv[j][0], lv[j][1]));
      u32 w1 = __builtin_bit_cast(u32, __builtin_amdgcn_cvt_pkrtz(lv[j][2], lv[j][3]));
      *(uint2*)(kb_ + r * 512 + ((2 * sh0) ^ ((r & 7) << 4))) = make_uint2(w0, w1);
    }
#pragma unroll
    for (int u = 0; u < 4; ++u) {
      int h = sh0 + u;
      int slot = h ^ ((h >> 3) & 7) ^ vrw;
      u32 w0 = __builtin_bit_cast(u32, __builtin_amdgcn_cvt_pkrtz(lv[0][u], lv[1][u]));
      u32 w1 = __builtin_bit_cast(u32, __builtin_amdgcn_cvt_pkrtz(lv[2][u], lv[3][u]));
      *(uint2*)(vb_ + vrw * 4096 + slot * 16 + 8 * half) = make_uint2(w0, w1);
    }
  };

  auto QK = [&](int buf) -> floatx16 {
    const unsigned char* kb_ = smem + buf * 16384;
    floatx16 S;
#pragma unroll
    for (int i = 0; i < 16; ++i) S[i] = 0.f;
    const int krow = l31 * 512;
    const int kx = (l31 & 7) << 4;
    __builtin_amdgcn_s_setprio(1);
#pragma unroll
    for (int c = 0; c < 16; ++c) {
      half8 a = *(const half8*)(kb_ + krow + ((c * 32 + g2 * 16) ^ kx));
      S = __builtin_amdgcn_mfma_f32_32x32x16_f16(a, qf[c], S, 0, 0, 0);
    }
    __builtin_amdgcn_s_setprio(0);
    return S;
  };

  auto SMPV = [&](int buf, floatx16 S) {
    const unsigned char* vb_ = smem + 32768 + buf * 16384;
    // lane owns q = l31 (both g2 copies); kk = (i&3)+8*(i>>2)+4*g2
    float lmax = S[0];
#pragma unroll
    for (int i = 1; i < 16; ++i) lmax = fmaxf(lmax, S[i]);
    lmax = fmaxf(lmax, __shfl_xor(lmax, 32));
    if (__any(lmax > mrun + 8.f)) {  // defer-max (T13)
      float mn = fmaxf(mrun, lmax);
      float al = __expf(mrun - mn);
      lrun *= al;
      mrun = mn;
#pragma unroll
      for (int i = 0; i < 16; ++i) {
        int qn = (i & 3) + 8 * (i >> 2) + 4 * g2;
        float aq = __shfl(al, qn);
#pragma unroll
        for (int t = 0; t < 8; ++t) ctx[t][i] *= aq;
      }
    }
    float p[16];
    float rs = 0.f;
#pragma unroll
    for (int i = 0; i < 16; ++i) {
      p[i] = __expf(S[i] - mrun);
      rs += p[i];
    }
    rs += __shfl_xor(rs, 32);
    lrun += rs;
    // pack P to f16, assemble PV A-fragments in-register
    u32 ph[8];
#pragma unroll
    for (int k2 = 0; k2 < 8; ++k2)
      ph[k2] = __builtin_bit_cast(u32, __builtin_amdgcn_cvt_pkrtz(p[2 * k2], p[2 * k2 + 1]));
#pragma unroll
    for (int c = 0; c < 2; ++c) {
      u32 a0 = ph[4 * c + 2 * g2], a1 = ph[4 * c + 2 * g2 + 1];
      u32 t0 = ph[4 * c + 2 * (1 - g2)], t1 = ph[4 * c + 2 * (1 - g2) + 1];
      u32 r0 = (u32)__shfl_xor((int)t0, 32);
      u32 r1 = (u32)__shfl_xor((int)t1, 32);
      union { u32 u[4]; half8 h8; } pf;
      if (g2 == 0) { pf.u[0] = a0; pf.u[1] = a1; pf.u[2] = r0; pf.u[3] = r1; }
      else         { pf.u[0] = r0; pf.u[1] = r1; pf.u[2] = a0; pf.u[3] = a1; }
      const int vrow = 2 * c + g2;
      const unsigned char* vr = vb_ + vrow * 4096;
      __builtin_amdgcn_s_setprio(1);
#pragma unroll
      for (int ht = 0; ht < 8; ++ht) {
        int h = ht * 32 + l31;
        int slot = h ^ ((h >> 3) & 7) ^ vrow;
        half8 vf = *(const half8*)(vr + slot * 16);
        ctx[ht] = __builtin_amdgcn_mfma_f32_32x32x16_f16(pf.h8, vf, ctx[ht], 0, 0, 0);
      }
      __builtin_amdgcn_s_setprio(0);
    }
  };

  // ---- pipeline: half-staged issue-early/write-late (T14), dbuf LDS ----
  LOADH(0, 0, la);
  WRITEH(0, 0, la);
  LOADH(0, 1, lb);
  WRITEH(0, 1, lb);
  __syncthreads();
  for (int sc = 0; sc < NSUB; ++sc) {
    const int cur = sc & 1, nxt = cur ^ 1;
    const bool pfv = (sc + 1 < NSUB);
    if (pfv) LOADH(sc + 1, 0, la);          // covered by QK
    floatx16 S = QK(cur);
    if (pfv) {
      WRITEH(nxt, 0, la);
      LOADH(sc + 1, 1, lb);                 // covered by softmax+PV
    }
    SMPV(cur, S);
    if (pfv) WRITEH(nxt, 1, lb);
    __syncthreads();
  }

  // ---- epilogue: normalized partials, packed u32, coalesced ----
  float rl = 1.0f / lrun;
  float rlq[16];
#pragma unroll
  for (int i = 0; i < 16; ++i)
    rlq[i] = __shfl(rl, (i & 3) + 8 * (i >> 2) + 4 * g2);
  u32* pbase = pctx + (((size_t)(ks * NB + b) * 4 + wave) << 12);  // *4096
#pragma unroll
  for (int ht = 0; ht < 8; ++ht)
#pragma unroll
    for (int j = 0; j < 8; ++j) {
      float v0 = ctx[ht][2 * j] * rlq[2 * j];
      float v1 = ctx[ht][2 * j + 1] * rlq[2 * j + 1];
      pbase[(ht * 8 + j) * 64 + lane] =
          __builtin_bit_cast(u32, __builtin_amdgcn_cvt_pkrtz(v0, v1));
    }
  if (g2 == 0) {
    float* mp = pml + ((size_t)ks * (NB * TQ) + b * TQ + wave * 32 + l31) * 2;
    mp[0] = mrun;
    mp[1] = lrun;
  }
}

__global__ __launch_bounds__(256) void attn_combine(
    const u32* __restrict__ pctx, const float* __restrict__ pml,
    float* __restrict__ out) {
  const int bq = blockIdx.x;  // b*128 + q
  const int b = bq >> 7, q = bq & 127;
  const int h = threadIdx.x;
  const int wq = q >> 5, qn = q & 31;
  const int g2 = (qn >> 2) & 1;
  const int i = (qn & 3) + 4 * (qn >> 3);
  const int j = i >> 1, b0 = i & 1;
  const int ht = h >> 5;
  const int ln = g2 * 32 + (h & 31);
  const size_t boff = (((size_t)b * 4 + wq) << 12) + (ht * 8 + j) * 64 + ln;

  float mv[KSPLIT], lvv[KSPLIT];
  float M = -1e30f;
#pragma unroll
  for (int s = 0; s < KSPLIT; ++s) {
    const float* mp = pml + ((size_t)s * (NB * TQ) + bq) * 2;
    mv[s] = mp[0];
    lvv[s] = mp[1];
    M = fmaxf(M, mv[s]);
  }
  float ssum = 0.f, acc = 0.f;
#pragma unroll
  for (int s = 0; s < KSPLIT; ++s) {
    float w = lvv[s] * __expf(mv[s] - M);
    ssum += w;
    union { u32 u; _Float16 hx[2]; } cv;
    cv.u = pctx[(size_t)s * (NB * 4 * 4096) + boff];
    acc += w * (float)cv.hx[b0];
  }
  out[(size_t)bq * HD + h] = acc / ssum;
}

extern "C" void kernel_launch(void* const* d_in, const int* in_sizes, int n_in,
                              void* d_out, int out_size, void* d_ws, size_t ws_size,
                              hipStream_t stream) {
  const float* enc = (const float*)d_in[0];
  const float* dec = (const float*)d_in[1];
  float* out = (float*)d_out;
  u32* pctx = (u32*)d_ws;
  float* pml = (float*)((unsigned char*)d_ws +
                        (size_t)KSPLIT * NB * 4 * 4096 * sizeof(u32));  // 32 MiB
  hipLaunchKernelGGL(attn_main, dim3(NB * KSPLIT), dim3(256), 0, stream,
                     enc, dec, pctx, pml);
  hipLaunchKernelGGL(attn_combine, dim3(NB * TQ), dim3(256), 0, stream,
                     pctx, pml, out);
}

// Round 3
// 86.733 us; speedup vs baseline: 1.6935x; 1.6935x over previous
//
#include <hip/hip_runtime.h>
#include <hip/hip_bf16.h>

// AttentionDot: B=16, TQ=128, TK=8192, H=256, fp32 in/out.
// Flash split-K attention, f16 MFMA 32x32x16, fp32 accumulate.
// Main: 256 blocks (b x 16 ksplits) x 512 thr (8 waves: 4 q-tiles x 2 h-halves),
//       1 block/CU, depth-2 register prefetch, counted-vmcnt barriers.
// ws: 16 MiB packed-f16 partial ctx + 256 KiB fp32 (m,l).

typedef _Float16 half8 __attribute__((ext_vector_type(8)));
typedef float floatx16 __attribute__((ext_vector_type(16)));
typedef unsigned int u32;

#define NB 16
#define TQ 128
#define TK 8192
#define HD 256
#define KSPLIT 16
#define KEYS_PER_SPLIT (TK / KSPLIT) /* 512 */
#define KB 32
#define NSUB (KEYS_PER_SPLIT / KB)   /* 16 */

// Barrier WITHOUT vmcnt drain: LDS writes visible (lgkmcnt 0), register
// global-loads stay in flight across the barrier (T4 counted-vmcnt idea).
#define BARRIER() asm volatile("s_waitcnt lgkmcnt(0)\n\ts_barrier" ::: "memory")

// LDS (64 KiB):
//   K bufs: 2 x [32 k][256 h] f16, row 512B, byte-in-row = (2h)^((k&7)<<4)   @ 0, 16384
//   V bufs: 2 x [4 vrow=kk>>3][256 slot][8 kk&7] f16, slot = h^((h>>3)&7)^vrow @ 32768, 49152

__global__ __launch_bounds__(512, 2) void attn_main(
    const float* __restrict__ enc, const float* __restrict__ dec,
    u32* __restrict__ pctx, float* __restrict__ pml) {
  __shared__ __align__(16) unsigned char smem[65536];
  const int tid = threadIdx.x;
  const int lane = tid & 63, wave = tid >> 6;
  const int wq = wave & 3;   // q-tile (32 rows)
  const int wh = wave >> 2;  // h half (0..1)
  const int l31 = lane & 31, g2 = lane >> 5;
  const int b = blockIdx.x >> 4, ks = blockIdx.x & 15;

  // ---- Q fragments in registers: qf[c] holds Q[q=l31][c*16 + g2*8 + j] ----
  half8 qf[16];
  {
    const float* qrow = dec + (size_t)(b * TQ + wq * 32 + l31) * HD;
#pragma unroll
    for (int c = 0; c < 16; ++c) {
      const float4* p4 = (const float4*)(qrow + c * 16 + g2 * 8);
      float4 x = p4[0], y = p4[1];
      half8 v;
      v[0] = (_Float16)x.x; v[1] = (_Float16)x.y; v[2] = (_Float16)x.z; v[3] = (_Float16)x.w;
      v[4] = (_Float16)y.x; v[5] = (_Float16)y.y; v[6] = (_Float16)y.z; v[7] = (_Float16)y.w;
      qf[c] = v;
    }
  }

  floatx16 ctx[4];
#pragma unroll
  for (int t = 0; t < 4; ++t)
#pragma unroll
    for (int i = 0; i < 16; ++i) ctx[t][i] = 0.f;
  float mrun = -1e30f, lrun = 0.f;

  const size_t keybase = (size_t)b * TK + (size_t)ks * KEYS_PER_SPLIT;
  const int sh0 = (tid & 63) * 4;   // 4 h columns per thread
  const int sr0 = (tid >> 6) * 4;   // 4 key rows per thread
  const int srv = (tid >> 6) >> 1;  // V row block (kk>>3)
  const int sa = (tid >> 6) & 1;    // which 8B half of the 16B V slot

  float la[4][4], lb[4][4];  // two prefetch register sets (depth-2)

  auto LOAD = [&](int sc, float (&lv)[4][4]) {
#pragma unroll
    for (int j = 0; j < 4; ++j) {
      float4 t = *(const float4*)(
          enc + (keybase + (size_t)sc * KB + sr0 + j) * HD + sh0);
      lv[j][0] = t.x; lv[j][1] = t.y; lv[j][2] = t.z; lv[j][3] = t.w;
    }
  };

  auto WRITE = [&](int buf, float (&lv)[4][4]) {
    unsigned char* kb_ = smem + buf * 16384;
    unsigned char* vb_ = smem + 32768 + buf * 16384;
#pragma unroll
    for (int j = 0; j < 4; ++j) {
      int r = sr0 + j;
      u32 w0 = __builtin_bit_cast(u32, __builtin_amdgcn_cvt_pkrtz(lv[j][0], lv[j][1]));
      u32 w1 = __builtin_bit_cast(u32, __builtin_amdgcn_cvt_pkrtz(lv[j][2], lv[j][3]));
      *(uint2*)(kb_ + r * 512 + ((2 * sh0) ^ ((r & 7) << 4))) = make_uint2(w0, w1);
    }
#pragma unroll
    for (int u = 0; u < 4; ++u) {
      int h = sh0 + u;
      int slot = h ^ ((h >> 3) & 7) ^ srv;
      u32 w0 = __builtin_bit_cast(u32, __builtin_amdgcn_cvt_pkrtz(lv[0][u], lv[1][u]));
      u32 w1 = __builtin_bit_cast(u32, __builtin_amdgcn_cvt_pkrtz(lv[2][u], lv[3][u]));
      *(uint2*)(vb_ + srv * 4096 + slot * 16 + 8 * sa) = make_uint2(w0, w1);
    }
  };

  auto COMPUTE = [&](int buf) {
    const unsigned char* kb_ = smem + buf * 16384;
    const unsigned char* vb_ = smem + 32768 + buf * 16384;
    // ---- GEMM1: S^T[kk, q] = K . Q^T ----
    floatx16 S;
#pragma unroll
    for (int i = 0; i < 16; ++i) S[i] = 0.f;
    const int krow = l31 * 512;
    const int kx = (l31 & 7) << 4;
    __builtin_amdgcn_s_setprio(1);
#pragma unroll
    for (int c = 0; c < 16; ++c) {
      half8 a = *(const half8*)(kb_ + krow + ((c * 32 + g2 * 16) ^ kx));
      S = __builtin_amdgcn_mfma_f32_32x32x16_f16(a, qf[c], S, 0, 0, 0);
    }
    __builtin_amdgcn_s_setprio(0);
    // ---- online softmax; lane owns q = l31; kk = (i&3)+8*(i>>2)+4*g2 ----
    float lmax = S[0];
#pragma unroll
    for (int i = 1; i < 16; ++i) lmax = fmaxf(lmax, S[i]);
    lmax = fmaxf(lmax, __shfl_xor(lmax, 32));
    if (__any(lmax > mrun + 8.f)) {  // defer-max (T13)
      float mn = fmaxf(mrun, lmax);
      float al = __expf(mrun - mn);
      lrun *= al;
      mrun = mn;
#pragma unroll
      for (int i = 0; i < 16; ++i) {
        int qn = (i & 3) + 8 * (i >> 2) + 4 * g2;
        float aq = __shfl(al, qn);
#pragma unroll
        for (int t = 0; t < 4; ++t) ctx[t][i] *= aq;
      }
    }
    float rs = 0.f;
#pragma unroll
    for (int i = 0; i < 16; ++i) {  // reuse S as P (register economy)
      S[i] = __expf(S[i] - mrun);
      rs += S[i];
    }
    rs += __shfl_xor(rs, 32);
    lrun += rs;
    // ---- pack P to f16, assemble PV A-fragments in-register ----
    u32 ph[8];
#pragma unroll
    for (int k2 = 0; k2 < 8; ++k2)
      ph[k2] = __builtin_bit_cast(u32, __builtin_amdgcn_cvt_pkrtz(S[2 * k2], S[2 * k2 + 1]));
#pragma unroll
    for (int c = 0; c < 2; ++c) {
      u32 a0 = ph[4 * c + 2 * g2], a1 = ph[4 * c + 2 * g2 + 1];
      u32 t0 = ph[4 * c + 2 * (1 - g2)], t1 = ph[4 * c + 2 * (1 - g2) + 1];
      u32 r0 = (u32)__shfl_xor((int)t0, 32);
      u32 r1 = (u32)__shfl_xor((int)t1, 32);
      union { u32 u[4]; half8 h8; } pf;
      if (g2 == 0) { pf.u[0] = a0; pf.u[1] = a1; pf.u[2] = r0; pf.u[3] = r1; }
      else         { pf.u[0] = r0; pf.u[1] = r1; pf.u[2] = a0; pf.u[3] = a1; }
      const int vrow = 2 * c + g2;
      const unsigned char* vr = vb_ + vrow * 4096;
      __builtin_amdgcn_s_setprio(1);
#pragma unroll
      for (int ht = 0; ht < 4; ++ht) {
        int h = wh * 128 + ht * 32 + l31;
        int slot = h ^ ((h >> 3) & 7) ^ vrow;
        half8 vf = *(const half8*)(vr + slot * 16);
        ctx[ht] = __builtin_amdgcn_mfma_f32_32x32x16_f16(pf.h8, vf, ctx[ht], 0, 0, 0);
      }
      __builtin_amdgcn_s_setprio(0);
    }
  };

  // ---- pipeline: depth-2 prefetch; loads stay in flight across barriers ----
  LOAD(0, la);
  LOAD(1, lb);
  WRITE(0, la);  // one-time vmcnt stall (counted: waits only la's loads)
  BARRIER();
  for (int sc = 0; sc < NSUB; ++sc) {
    if (sc + 2 < NSUB) LOAD(sc + 2, (sc & 1) ? lb : la);  // ~1 full iter ahead
    COMPUTE(sc & 1);
    if (sc + 1 < NSUB) WRITE((sc + 1) & 1, (sc & 1) ? la : lb);  // data long arrived
    BARRIER();
  }

  // ---- epilogue: normalized partials, packed u32, lane-major coalesced ----
  float rl = 1.0f / lrun;
  float rlq[16];
#pragma unroll
  for (int i = 0; i < 16; ++i)
    rlq[i] = __shfl(rl, (i & 3) + 8 * (i >> 2) + 4 * g2);
  // layout: [ks][b][wq(4)][wh(2)][ht(4)][j(8)][lane(64)] u32
  u32* pbase = pctx + (size_t)(ks * NB + b) * 16384 + (wq * 2 + wh) * 2048;
#pragma unroll
  for (int ht = 0; ht < 4; ++ht)
#pragma unroll
    for (int j = 0; j < 8; ++j) {
      float v0 = ctx[ht][2 * j] * rlq[2 * j];
      float v1 = ctx[ht][2 * j + 1] * rlq[2 * j + 1];
      pbase[(ht * 8 + j) * 64 + lane] =
          __builtin_bit_cast(u32, __builtin_amdgcn_cvt_pkrtz(v0, v1));
    }
  if (wh == 0 && g2 == 0) {
    float* mp = pml + ((size_t)ks * (NB * TQ) + b * TQ + wq * 32 + l31) * 2;
    mp[0] = mrun;
    mp[1] = lrun;
  }
}

__global__ __launch_bounds__(256) void attn_combine(
    const u32* __restrict__ pctx, const float* __restrict__ pml,
    float* __restrict__ out) {
  const int bq = blockIdx.x;  // b*128 + q
  const int b = bq >> 7, q = bq & 127;
  const int h = threadIdx.x;
  const int wq = q >> 5, qn = q & 31;
  const int g2 = (qn >> 2) & 1;
  const int i = (qn & 3) + 4 * (qn >> 3);  // q = (i&3)+8*(i>>2)+4*g2
  const int j = i >> 1, b0 = i & 1;
  const int wh = h >> 7, ht = (h >> 5) & 3;
  const int ln = (h & 31) + 32 * g2;
  const size_t boff = (size_t)b * 16384 + (wq * 2 + wh) * 2048 + (ht * 8 + j) * 64 + ln;

  float mv[KSPLIT], lvv[KSPLIT];
  float M = -1e30f;
#pragma unroll
  for (int s = 0; s < KSPLIT; ++s) {
    const float* mp = pml + ((size_t)s * (NB * TQ) + bq) * 2;
    mv[s] = mp[0];
    lvv[s] = mp[1];
    M = fmaxf(M, mv[s]);
  }
  float ssum = 0.f, acc = 0.f;
#pragma unroll
  for (int s = 0; s < KSPLIT; ++s) {
    float w = lvv[s] * __expf(mv[s] - M);
    ssum += w;
    union { u32 u; _Float16 hx[2]; } cv;
    cv.u = pctx[(size_t)s * (NB * 16384) + boff];
    acc += w * (float)cv.hx[b0];
  }
  out[(size_t)bq * HD + h] = acc / ssum;
}

extern "C" void kernel_launch(void* const* d_in, const int* in_sizes, int n_in,
                              void* d_out, int out_size, void* d_ws, size_t ws_size,
                              hipStream_t stream) {
  const float* enc = (const float*)d_in[0];
  const float* dec = (const float*)d_in[1];
  float* out = (float*)d_out;
  u32* pctx = (u32*)d_ws;
  float* pml = (float*)((unsigned char*)d_ws +
                        (size_t)KSPLIT * NB * 16384 * sizeof(u32));  // 16 MiB
  hipLaunchKernelGGL(attn_main, dim3(NB * KSPLIT), dim3(512), 0, stream,
                     enc, dec, pctx, pml);
  hipLaunchKernelGGL(attn_combine, dim3(NB * TQ), dim3(256), 0, stream,
                     pctx, pml, out);
}

// Round 4
// 69.571 us; speedup vs baseline: 2.1112x; 1.2467x over previous
//
#include <hip/hip_runtime.h>
#include <hip/hip_bf16.h>

// AttentionDot: B=16, TQ=128, TK=8192, H=256, fp32 in/out.
// Flash split-K attention, f16 MFMA 32x32x16, fp32 accumulate.
// Main: 256 blocks (b x 16 ksplits) x 512 thr (8 waves: 4 q-tiles x 2 h-halves),
//       1 block/CU, depth-1 in-iteration prefetch (R1 skeleton),
//       waves_per_eu(2,2) pins 256-reg budget -> no spills.
// ws: 16 MiB packed-f16 partial ctx + 256 KiB fp32 (m,l).

typedef _Float16 half8 __attribute__((ext_vector_type(8)));
typedef float floatx16 __attribute__((ext_vector_type(16)));
typedef unsigned int u32;

#define NB 16
#define TQ 128
#define TK 8192
#define HD 256
#define KSPLIT 16
#define KEYS_PER_SPLIT (TK / KSPLIT) /* 512 */
#define KB 32
#define NSUB (KEYS_PER_SPLIT / KB)   /* 16 */

// LDS (64 KiB):
//   K bufs: 2 x [32 k][256 h] f16, row 512B, byte-in-row = (2h)^((k&7)<<4)   @ 0, 16384
//   V bufs: 2 x [4 vrow=kk>>3][256 slot][8 kk&7] f16, slot = h^((h>>3)&7)^vrow @ 32768, 49152

__global__ __attribute__((amdgpu_flat_work_group_size(512, 512)))
__attribute__((amdgpu_waves_per_eu(2, 2))) void attn_main(
    const float* __restrict__ enc, const float* __restrict__ dec,
    u32* __restrict__ pctx, float* __restrict__ pml) {
  __shared__ __align__(16) unsigned char smem[65536];
  const int tid = threadIdx.x;
  const int lane = tid & 63, wave = tid >> 6;
  const int wq = wave & 3;   // q-tile (32 rows)
  const int wh = wave >> 2;  // h half (0..1)
  const int l31 = lane & 31, g2 = lane >> 5;
  const int b = blockIdx.x >> 4, ks = blockIdx.x & 15;

  // ---- Q fragments in registers: qf[c] holds Q[q=l31][c*16 + g2*8 + j] ----
  half8 qf[16];
  {
    const float* qrow = dec + (size_t)(b * TQ + wq * 32 + l31) * HD;
#pragma unroll
    for (int c = 0; c < 16; ++c) {
      const float4* p4 = (const float4*)(qrow + c * 16 + g2 * 8);
      float4 x = p4[0], y = p4[1];
      half8 v;
      v[0] = (_Float16)x.x; v[1] = (_Float16)x.y; v[2] = (_Float16)x.z; v[3] = (_Float16)x.w;
      v[4] = (_Float16)y.x; v[5] = (_Float16)y.y; v[6] = (_Float16)y.z; v[7] = (_Float16)y.w;
      qf[c] = v;
    }
  }

  floatx16 ctx[4];
#pragma unroll
  for (int t = 0; t < 4; ++t)
#pragma unroll
    for (int i = 0; i < 16; ++i) ctx[t][i] = 0.f;
  float mrun = -1e30f, lrun = 0.f;

  const size_t keybase = (size_t)b * TK + (size_t)ks * KEYS_PER_SPLIT;
  const int sh0 = (tid & 63) * 4;   // 4 h columns per thread
  const int sr0 = (tid >> 6) * 4;   // 4 key rows per thread
  const int srv = (tid >> 6) >> 1;  // V row block (kk>>3)
  const int sa = (tid >> 6) & 1;    // which 8B half of the 16B V slot

  float la[4][4];  // depth-1 staging registers (live only LOAD->WRITE)

  auto LOAD = [&](int sc) {
#pragma unroll
    for (int j = 0; j < 4; ++j) {
      float4 t = *(const float4*)(
          enc + (keybase + (size_t)sc * KB + sr0 + j) * HD + sh0);
      la[j][0] = t.x; la[j][1] = t.y; la[j][2] = t.z; la[j][3] = t.w;
    }
  };

  auto WRITE = [&](int buf) {
    unsigned char* kb_ = smem + buf * 16384;
    unsigned char* vb_ = smem + 32768 + buf * 16384;
#pragma unroll
    for (int j = 0; j < 4; ++j) {
      int r = sr0 + j;
      u32 w0 = __builtin_bit_cast(u32, __builtin_amdgcn_cvt_pkrtz(la[j][0], la[j][1]));
      u32 w1 = __builtin_bit_cast(u32, __builtin_amdgcn_cvt_pkrtz(la[j][2], la[j][3]));
      *(uint2*)(kb_ + r * 512 + ((2 * sh0) ^ ((r & 7) << 4))) = make_uint2(w0, w1);
    }
#pragma unroll
    for (int u = 0; u < 4; ++u) {
      int h = sh0 + u;
      int slot = h ^ ((h >> 3) & 7) ^ srv;
      u32 w0 = __builtin_bit_cast(u32, __builtin_amdgcn_cvt_pkrtz(la[0][u], la[1][u]));
      u32 w1 = __builtin_bit_cast(u32, __builtin_amdgcn_cvt_pkrtz(la[2][u], la[3][u]));
      *(uint2*)(vb_ + srv * 4096 + slot * 16 + 8 * sa) = make_uint2(w0, w1);
    }
  };

  auto COMPUTE = [&](int buf) {
    const unsigned char* kb_ = smem + buf * 16384;
    const unsigned char* vb_ = smem + 32768 + buf * 16384;
    // ---- GEMM1: S^T[kk, q] = K . Q^T ----
    floatx16 S;
#pragma unroll
    for (int i = 0; i < 16; ++i) S[i] = 0.f;
    const int krow = l31 * 512;
    const int kx = (l31 & 7) << 4;
#pragma unroll
    for (int c = 0; c < 16; ++c) {
      half8 a = *(const half8*)(kb_ + krow + ((c * 32 + g2 * 16) ^ kx));
      S = __builtin_amdgcn_mfma_f32_32x32x16_f16(a, qf[c], S, 0, 0, 0);
    }
    // ---- online softmax; lane owns q = l31; kk = (i&3)+8*(i>>2)+4*g2 ----
    float lmax = S[0];
#pragma unroll
    for (int i = 1; i < 16; ++i) lmax = fmaxf(lmax, S[i]);
    lmax = fmaxf(lmax, __shfl_xor(lmax, 32));
    if (__any(lmax > mrun + 10.f)) {  // defer-max (T13), THR=10
      float mn = fmaxf(mrun, lmax);
      float al = __expf(mrun - mn);
      lrun *= al;
      mrun = mn;
#pragma unroll
      for (int i = 0; i < 16; ++i) {
        int qn = (i & 3) + 8 * (i >> 2) + 4 * g2;
        float aq = __shfl(al, qn);
#pragma unroll
        for (int t = 0; t < 4; ++t) ctx[t][i] *= aq;
      }
    }
    float rs = 0.f;
#pragma unroll
    for (int i = 0; i < 16; ++i) {  // reuse S as P (register economy)
      S[i] = __expf(S[i] - mrun);
      rs += S[i];
    }
    rs += __shfl_xor(rs, 32);
    lrun += rs;
    // ---- pack P to f16, assemble PV A-fragments in-register ----
    u32 ph[8];
#pragma unroll
    for (int k2 = 0; k2 < 8; ++k2)
      ph[k2] = __builtin_bit_cast(u32, __builtin_amdgcn_cvt_pkrtz(S[2 * k2], S[2 * k2 + 1]));
#pragma unroll
    for (int c = 0; c < 2; ++c) {
      u32 a0 = ph[4 * c + 2 * g2], a1 = ph[4 * c + 2 * g2 + 1];
      u32 t0 = ph[4 * c + 2 * (1 - g2)], t1 = ph[4 * c + 2 * (1 - g2) + 1];
      u32 r0 = (u32)__shfl_xor((int)t0, 32);
      u32 r1 = (u32)__shfl_xor((int)t1, 32);
      union { u32 u[4]; half8 h8; } pf;
      if (g2 == 0) { pf.u[0] = a0; pf.u[1] = a1; pf.u[2] = r0; pf.u[3] = r1; }
      else         { pf.u[0] = r0; pf.u[1] = r1; pf.u[2] = a0; pf.u[3] = a1; }
      const int vrow = 2 * c + g2;
      const unsigned char* vr = vb_ + vrow * 4096;
      __builtin_amdgcn_s_setprio(1);
#pragma unroll
      for (int ht = 0; ht < 4; ++ht) {
        int h = wh * 128 + ht * 32 + l31;
        int slot = h ^ ((h >> 3) & 7) ^ vrow;
        half8 vf = *(const half8*)(vr + slot * 16);
        ctx[ht] = __builtin_amdgcn_mfma_f32_32x32x16_f16(pf.h8, vf, ctx[ht], 0, 0, 0);
      }
      __builtin_amdgcn_s_setprio(0);
    }
  };

  // ---- pipeline (R1 skeleton): depth-1, load covered by COMPUTE ----
  LOAD(0);
  WRITE(0);
  __syncthreads();
  for (int sc = 0; sc < NSUB; ++sc) {
    if (sc + 1 < NSUB) LOAD(sc + 1);
    COMPUTE(sc & 1);
    if (sc + 1 < NSUB) WRITE((sc + 1) & 1);
    __syncthreads();
  }

  // ---- epilogue: normalized partials, packed u32, lane-major coalesced ----
  float rl = 1.0f / lrun;
  float rlq[16];
#pragma unroll
  for (int i = 0; i < 16; ++i)
    rlq[i] = __shfl(rl, (i & 3) + 8 * (i >> 2) + 4 * g2);
  // layout: [ks][b][wq(4)][wh(2)][ht(4)][j(8)][lane(64)] u32
  u32* pbase = pctx + (size_t)(ks * NB + b) * 16384 + (wq * 2 + wh) * 2048;
#pragma unroll
  for (int ht = 0; ht < 4; ++ht)
#pragma unroll
    for (int j = 0; j < 8; ++j) {
      float v0 = ctx[ht][2 * j] * rlq[2 * j];
      float v1 = ctx[ht][2 * j + 1] * rlq[2 * j + 1];
      pbase[(ht * 8 + j) * 64 + lane] =
          __builtin_bit_cast(u32, __builtin_amdgcn_cvt_pkrtz(v0, v1));
    }
  if (wh == 0 && g2 == 0) {
    float* mp = pml + ((size_t)ks * (NB * TQ) + b * TQ + wq * 32 + l31) * 2;
    mp[0] = mrun;
    mp[1] = lrun;
  }
}

__global__ __launch_bounds__(256) void attn_combine(
    const u32* __restrict__ pctx, const float* __restrict__ pml,
    float* __restrict__ out) {
  const int bq = blockIdx.x;  // b*128 + q
  const int b = bq >> 7, q = bq & 127;
  const int h = threadIdx.x;
  const int wq = q >> 5, qn = q & 31;
  const int g2 = (qn >> 2) & 1;
  const int i = (qn & 3) + 4 * (qn >> 3);  // q = (i&3)+8*(i>>2)+4*g2
  const int j = i >> 1, b0 = i & 1;
  const int wh = h >> 7, ht = (h >> 5) & 3;
  const int ln = (h & 31) + 32 * g2;
  const size_t boff = (size_t)b * 16384 + (wq * 2 + wh) * 2048 + (ht * 8 + j) * 64 + ln;

  float mv[KSPLIT], lvv[KSPLIT];
  float M = -1e30f;
#pragma unroll
  for (int s = 0; s < KSPLIT; ++s) {
    const float* mp = pml + ((size_t)s * (NB * TQ) + bq) * 2;
    mv[s] = mp[0];
    lvv[s] = mp[1];
    M = fmaxf(M, mv[s]);
  }
  float ssum = 0.f, acc = 0.f;
#pragma unroll
  for (int s = 0; s < KSPLIT; ++s) {
    float w = lvv[s] * __expf(mv[s] - M);
    ssum += w;
    union { u32 u; _Float16 hx[2]; } cv;
    cv.u = pctx[(size_t)s * (NB * 16384) + boff];
    acc += w * (float)cv.hx[b0];
  }
  out[(size_t)bq * HD + h] = acc / ssum;
}

extern "C" void kernel_launch(void* const* d_in, const int* in_sizes, int n_in,
                              void* d_out, int out_size, void* d_ws, size_t ws_size,
                              hipStream_t stream) {
  const float* enc = (const float*)d_in[0];
  const float* dec = (const float*)d_in[1];
  float* out = (float*)d_out;
  u32* pctx = (u32*)d_ws;
  float* pml = (float*)((unsigned char*)d_ws +
                        (size_t)KSPLIT * NB * 16384 * sizeof(u32));  // 16 MiB
  hipLaunchKernelGGL(attn_main, dim3(NB * KSPLIT), dim3(512), 0, stream,
                     enc, dec, pctx, pml);
  hipLaunchKernelGGL(attn_combine, dim3(NB * TQ), dim3(256), 0, stream,
                     pctx, pml, out);
}